// Round 6
// baseline (151.698 us; speedup 1.0000x reference)
//
#include <hip/hip_runtime.h>
#include <hip/hip_bf16.h>

#define N_NODES 20000
#define N_EDGES 320000
#define BN_EPS  1e-5f

#define GEMM_MT  ((N_NODES + 127) / 128)    // 157
#define NGEMM    (GEMM_MT * 4)              // 628 GEMM blocks (first!)
#define FILLB    256                        // trailing fill blocks (grid-stride)

typedef __attribute__((ext_vector_type(4))) float f32x4;
typedef __attribute__((ext_vector_type(8))) __bf16 bf16x8;
typedef __attribute__((ext_vector_type(4))) unsigned short u16x4;

__device__ __forceinline__ unsigned short f2bf(float f) {   // RNE f32->bf16
    unsigned int u = __float_as_uint(f);
    u += 0x7fffu + ((u >> 16) & 1u);
    return (unsigned short)(u >> 16);
}
__device__ __forceinline__ float bflo(unsigned int u) { return __uint_as_float(u << 16); }
__device__ __forceinline__ float bfhi(unsigned int u) { return __uint_as_float(u & 0xffff0000u); }

__device__ __forceinline__ void gload_lds16(const void* g, void* l) {
    __builtin_amdgcn_global_load_lds(
        (const __attribute__((address_space(1))) void*)g,
        (__attribute__((address_space(3))) void*)l, 16, 0, 0);
}

// ---------------------------------------------------------------------------
// cvt + zero: convert x and the four W mats to bf16, and zero cnt/cur/stats
// (replaces hipMemsetAsync, whose fill dispatch cost ~41 us in the graph).
// ---------------------------------------------------------------------------
__global__ __launch_bounds__(256) void cvt_zero_kernel(
    const float* __restrict__ x,
    const float* __restrict__ Wlf, const float* __restrict__ Wlb,
    const float* __restrict__ Wrf, const float* __restrict__ Wrb,
    unsigned short* __restrict__ Xb, unsigned short* __restrict__ Wb,
    uint4* __restrict__ zp, int zquads)
{
    const int XQ = N_NODES * 256 / 4;         // 1,280,000
    const int WQ = 128 * 256 / 4;             // 8,192 per matrix
    const int total = XQ + 4 * WQ + zquads;
    for (int i = blockIdx.x * blockDim.x + threadIdx.x; i < total; i += gridDim.x * blockDim.x) {
        if (i >= XQ + 4 * WQ) {
            zp[i - XQ - 4 * WQ] = make_uint4(0, 0, 0, 0);
            continue;
        }
        const float* sp;
        unsigned short* dp;
        if (i < XQ) {
            sp = x + (size_t)i * 4;
            dp = Xb + (size_t)i * 4;
        } else {
            int w = i - XQ;
            int mat = w / WQ;
            int o = (w - mat * WQ) * 4;
            if      (mat == 0) sp = Wlf + o;
            else if (mat == 1) sp = Wlb + o;
            else if (mat == 2) sp = Wrf + o;
            else               sp = Wrb + o;
            dp = Wb + (size_t)mat * 32768 + o;
        }
        float4 v = *(const float4*)sp;
        u16x4 r = {f2bf(v.x), f2bf(v.y), f2bf(v.z), f2bf(v.w)};
        *(u16x4*)dp = r;
    }
}

// ---------------------------------------------------------------------------
// CSR build: count, scan
// ---------------------------------------------------------------------------
__global__ void count_kernel(const int* __restrict__ src, const int* __restrict__ dst,
                             int* __restrict__ cntF, int* __restrict__ cntB) {
    int e = blockIdx.x * blockDim.x + threadIdx.x;
    if (e < N_EDGES) {
        atomicAdd(&cntF[dst[e]], 1);
        atomicAdd(&cntB[src[e]], 1);
    }
}

#define SCAN_PER 20
__global__ __launch_bounds__(1024) void scan_kernel(const int* __restrict__ cntF, int* __restrict__ offF,
                                                    const int* __restrict__ cntB, int* __restrict__ offB) {
    const int* in  = blockIdx.x ? cntB : cntF;
    int*       out = blockIdx.x ? offB : offF;
    int t = threadIdx.x;
    int base = t * SCAN_PER;
    int v[SCAN_PER];
    int sum = 0;
    #pragma unroll
    for (int k = 0; k < SCAN_PER; ++k) {
        int i = base + k;
        int c = (i < N_NODES) ? in[i] : 0;
        v[k] = sum; sum += c;
    }
    __shared__ int sh[1024];
    sh[t] = sum;
    __syncthreads();
    for (int o = 1; o < 1024; o <<= 1) {
        int x = (t >= o) ? sh[t - o] : 0;
        __syncthreads();
        sh[t] += x;
        __syncthreads();
    }
    int pre = t ? sh[t - 1] : 0;
    #pragma unroll
    for (int k = 0; k < SCAN_PER; ++k) {
        int i = base + k;
        if (i < N_NODES) out[i] = pre + v[k];
    }
    if (t == 1023) out[N_NODES] = sh[1023];
}

// ---------------------------------------------------------------------------
// Merged GEMM + fill. GEMM blocks are FIRST (blockIdx 0..NGEMM-1) so they
// start immediately; fill is grid-strided over FILLB trailing blocks and
// co-runs in the GEMM's memory slack (round-5 had fill first -> serialized).
// GEMM: double-buffered BK=64 pipeline with counted vmcnt (T3/T4-lite):
//   STAGE(t+1) -> s_waitcnt vmcnt(8) -> s_barrier -> MFMA(t) -> s_barrier
// Raw s_barrier (NOT __syncthreads, which drains vmcnt(0)) keeps the next
// tile's 8 global_load_lds in flight across the barrier.
// XOR-swizzled staging (pre-swizzled source + swizzled ds_read; rule #21).
// ---------------------------------------------------------------------------
__global__ __launch_bounds__(256) void gemm_fill_kernel(
    const int* __restrict__ src, const int* __restrict__ dst,
    const int* __restrict__ offF, const int* __restrict__ offB,
    int* __restrict__ curF, int* __restrict__ curB,
    int* __restrict__ listF, int* __restrict__ listB,
    const unsigned short* __restrict__ Xb, const unsigned short* __restrict__ Wb,
    unsigned short* __restrict__ Y, float* __restrict__ Z)
{
    __shared__ unsigned short As[2][128 * 64];   // 2 x 16 KB
    __shared__ unsigned short Bs[2][128 * 64];   // 2 x 16 KB

    if (blockIdx.x >= NGEMM) {
        // CSR fill, grid-strided over FILLB blocks
        for (int e = (blockIdx.x - NGEMM) * 256 + threadIdx.x; e < N_EDGES; e += FILLB * 256) {
            int s = src[e], d = dst[e];
            int p = atomicAdd(&curF[d], 1);
            listF[offF[d] + p] = s;
            int q = atomicAdd(&curB[s], 1);
            listB[offB[s] + q] = d;
        }
        return;
    }

    int gb = blockIdx.x;
    int by = gb & 3;                 // 4 consecutive blocks share one Xb tile
    int mBase = (gb >> 2) * 128;
    int tid = threadIdx.x, lane = tid & 63, wave = tid >> 6;
    int wr = wave >> 1, wc = wave & 1;
    const unsigned short* W = Wb + (size_t)by * 128 * 256;

    f32x4 acc[4][4] = {};

    auto STAGE = [&](int b, int k0) {
        #pragma unroll
        for (int c = 0; c < 4; ++c) {
            int S = c * 256 + tid;                 // 16B slot index, 0..1023
            int row = S >> 3;
            int q = (S & 7) ^ (row & 7);           // pre-swizzled source slot
            int gm = mBase + row; gm = gm < N_NODES ? gm : N_NODES - 1;
            gload_lds16(Xb + (size_t)gm * 256 + k0 + q * 8, &As[b][S * 8]);
            gload_lds16(W + (size_t)row * 256 + k0 + q * 8, &Bs[b][S * 8]);
        }
    };
    auto COMPUTE = [&](int b) {
        #pragma unroll
        for (int ks = 0; ks < 2; ++ks) {
            bf16x8 af[4], bfr[4];
            int sl = ks * 4 + (lane >> 4);
            #pragma unroll
            for (int m = 0; m < 4; ++m) {
                int row = wr * 64 + m * 16 + (lane & 15);
                af[m] = *(const bf16x8*)&As[b][row * 64 + ((sl ^ (row & 7)) * 8)];
            }
            #pragma unroll
            for (int n = 0; n < 4; ++n) {
                int row = wc * 64 + n * 16 + (lane & 15);
                bfr[n] = *(const bf16x8*)&Bs[b][row * 64 + ((sl ^ (row & 7)) * 8)];
            }
            #pragma unroll
            for (int m = 0; m < 4; ++m)
                #pragma unroll
                for (int n = 0; n < 4; ++n)
                    acc[m][n] = __builtin_amdgcn_mfma_f32_16x16x32_bf16(af[m], bfr[n], acc[m][n], 0, 0, 0);
        }
    };

    STAGE(0, 0);                                   // prologue: tile 0 in flight
    #pragma unroll
    for (int t = 0; t < 4; ++t) {
        if (t < 3) {
            STAGE((t + 1) & 1, (t + 1) * 64);      // tile t+1 in flight (8 loads)
            asm volatile("s_waitcnt vmcnt(8)" ::: "memory");   // tile t done
        } else {
            asm volatile("s_waitcnt vmcnt(0)" ::: "memory");
        }
        __builtin_amdgcn_s_barrier();              // all waves: tile t ready
        __builtin_amdgcn_sched_barrier(0);
        COMPUTE(t & 1);
        __builtin_amdgcn_s_barrier();              // done reading buf before overwrite
    }

    bool toY = by < 2;
    int cBase = (by & 1) * 128 + wc * 64;
    #pragma unroll
    for (int m = 0; m < 4; ++m) {
        int gm0 = mBase + wr * 64 + m * 16 + (lane >> 4) * 4;
        #pragma unroll
        for (int n = 0; n < 4; ++n) {
            int gn = cBase + n * 16 + (lane & 15);
            f32x4 v = acc[m][n];
            #pragma unroll
            for (int j = 0; j < 4; ++j) {
                int gm = gm0 + j;
                if (gm < N_NODES) {
                    if (toY) Y[(size_t)gm * 256 + gn] = f2bf(v[j]);
                    else     Z[(size_t)gm * 256 + gn] = v[j];
                }
            }
        }
    }
}

// ---------------------------------------------------------------------------
// Aggregation: wave = one (node,dir) stream, 2 nodes/wave. 16 lanes cover one
// 128-col bf16 row (16B/lane), so one wave-load gathers 4 edges; 4 loads
// (16 edges) in flight. __shfl executes UNCONDITIONALLY (ds_bpermute reads 0
// from exec-inactive source lanes — round-4 bug); only the LOAD is predicated.
// Cross-group shfl_xor reduce, h = aggr/deg + Z.
// ---------------------------------------------------------------------------
#define NPW 2
__global__ __launch_bounds__(256) void aggregate_kernel(
    const unsigned short* __restrict__ Y,
    const int* __restrict__ offF, const int* __restrict__ listF,
    const int* __restrict__ offB, const int* __restrict__ listB,
    float* __restrict__ H)
{
    int tid = threadIdx.x, lane = tid & 63, wave = tid >> 6;
    int dir = wave >> 1, half = wave & 1;
    const int* off  = dir ? offB : offF;
    const int* list = dir ? listB : listF;
    int eg = lane >> 4;        // which edge of the group of 4
    int c16 = lane & 15;       // 16B column slot within the row
    int nodeBase = blockIdx.x * (2 * NPW) + half * NPW;

    for (int jn = 0; jn < NPW; ++jn) {
        int n = nodeBase + jn;                 // grid exact: always < N_NODES
        int beg = off[n], end = off[n + 1];
        int deg = end - beg;
        float acc[8] = {0.f, 0.f, 0.f, 0.f, 0.f, 0.f, 0.f, 0.f};

        for (int i = beg; i < end; i += 64) {
            int c = end - i; if (c > 64) c = 64;
            int u_l = list[i + (lane < c ? lane : 0)];
            for (int e0 = 0; e0 < c; e0 += 16) {
                uint4 v[4];
                #pragma unroll
                for (int k = 0; k < 4; ++k) {
                    int ei = e0 + k * 4 + eg;
                    // shfl with ALL lanes active (clamped index), then
                    // predicate only the memory access:
                    int u = __shfl(u_l, ei < c ? ei : 0);
                    v[k] = make_uint4(0u, 0u, 0u, 0u);
                    if (ei < c)
                        v[k] = *(const uint4*)(Y + (size_t)u * 256 + dir * 128 + c16 * 8);
                }
                #pragma unroll
                for (int k = 0; k < 4; ++k) {
                    acc[0] += bflo(v[k].x); acc[1] += bfhi(v[k].x);
                    acc[2] += bflo(v[k].y); acc[3] += bfhi(v[k].y);
                    acc[4] += bflo(v[k].z); acc[5] += bfhi(v[k].z);
                    acc[6] += bflo(v[k].w); acc[7] += bfhi(v[k].w);
                }
            }
        }
        #pragma unroll
        for (int j = 0; j < 8; ++j) {
            acc[j] += __shfl_xor(acc[j], 16);
            acc[j] += __shfl_xor(acc[j], 32);
        }
        // static-index select of this lane's two columns (rule #20)
        float h0 = (eg & 2) ? ((eg & 1) ? acc[6] : acc[4]) : ((eg & 1) ? acc[2] : acc[0]);
        float h1 = (eg & 2) ? ((eg & 1) ? acc[7] : acc[5]) : ((eg & 1) ? acc[3] : acc[1]);
        float inv = 1.f / fmaxf((float)deg, 1.f);
        float2* hp = (float2*)(H + (size_t)n * 256 + dir * 128 + c16 * 8 + eg * 2);
        float2 z = *hp;
        *hp = make_float2(fmaf(h0, inv, z.x), fmaf(h1, inv, z.y));
    }
}

// ---------------------------------------------------------------------------
// BN stats: column sums of H (coalesced, 512 atomics per block).
// ---------------------------------------------------------------------------
__global__ __launch_bounds__(256) void bn_stats_kernel(const float* __restrict__ H,
                                                       float* __restrict__ stats) {
    int col = threadIdx.x;
    float s1 = 0.f, s2 = 0.f;
    for (int n = blockIdx.x; n < N_NODES; n += gridDim.x) {
        float h = H[(size_t)n * 256 + col];
        s1 += h;
        s2 += h * h;
    }
    atomicAdd(&stats[col], s1);
    atomicAdd(&stats[256 + col], s2);
}

// ---------------------------------------------------------------------------
// BatchNorm finalize + ReLU, in place on d_out.
// ---------------------------------------------------------------------------
__global__ __launch_bounds__(256) void bn_kernel(
    const float* __restrict__ stats, const float* __restrict__ gamma,
    const float* __restrict__ beta, float* __restrict__ H)
{
    __shared__ float sc[256], sf[256];
    int tid = threadIdx.x;
    {
        float mean = stats[tid] * (1.f / N_NODES);
        float var  = stats[256 + tid] * (1.f / N_NODES) - mean * mean;
        float s = rsqrtf(fmaxf(var, 0.f) + BN_EPS) * gamma[tid];
        sc[tid] = s;
        sf[tid] = beta[tid] - mean * s;
    }
    __syncthreads();
    for (int n = blockIdx.x; n < N_NODES; n += gridDim.x) {
        size_t idx = (size_t)n * 256 + tid;
        float h = H[idx];
        H[idx] = fmaxf(h * sc[tid] + sf[tid], 0.f);
    }
}

// ---------------------------------------------------------------------------
extern "C" void kernel_launch(void* const* d_in, const int* in_sizes, int n_in,
                              void* d_out, int out_size, void* d_ws, size_t ws_size,
                              hipStream_t stream) {
    const float* x     = (const float*)d_in[0];
    const int*   edge  = (const int*)d_in[1];   // [2][N_EDGES]
    const float* Wlf   = (const float*)d_in[2];
    // d_in[3] = b_l_f : cancels under BatchNorm (per-column shift) - unused
    const float* Wrf   = (const float*)d_in[4];
    const float* Wlb   = (const float*)d_in[5];
    // d_in[6] = b_l_b : unused (cancels)
    const float* Wrb   = (const float*)d_in[7];
    const float* gamma = (const float*)d_in[8];
    const float* beta  = (const float*)d_in[9];
    float* out = (float*)d_out;

    const int* src = edge;
    const int* dst = edge + N_EDGES;

    char* ws = (char*)d_ws;
    size_t off = 0;
    auto alloc = [&](size_t bytes) { size_t r = off; off += (bytes + 255) & ~(size_t)255; return r; };
    unsigned short* Y  = (unsigned short*)(ws + alloc((size_t)N_NODES * 256 * 2)); // 10.24 MB
    unsigned short* Xb = (unsigned short*)(ws + alloc((size_t)N_NODES * 256 * 2)); // 10.24 MB
    unsigned short* Wb = (unsigned short*)(ws + alloc((size_t)4 * 128 * 256 * 2)); // 256 KB
    int* offF  = (int*)(ws + alloc((size_t)(N_NODES + 1) * 4));
    int* offB  = (int*)(ws + alloc((size_t)(N_NODES + 1) * 4));
    int* listF = (int*)(ws + alloc((size_t)N_EDGES * 4));
    int* listB = (int*)(ws + alloc((size_t)N_EDGES * 4));
    size_t zbase_off = off;
    int* cntF = (int*)(ws + alloc((size_t)N_NODES * 4));
    int* cntB = (int*)(ws + alloc((size_t)N_NODES * 4));
    int* curF = (int*)(ws + alloc((size_t)N_NODES * 4));
    int* curB = (int*)(ws + alloc((size_t)N_NODES * 4));
    float* stats = (float*)(ws + alloc(512 * 4));
    size_t zbytes = off - zbase_off;          // 256B-aligned => multiple of 16

    cvt_zero_kernel<<<2048, 256, 0, stream>>>(x, Wlf, Wlb, Wrf, Wrb, Xb, Wb,
                                              (uint4*)(ws + zbase_off), (int)(zbytes / 16));

    count_kernel<<<(N_EDGES + 255) / 256, 256, 0, stream>>>(src, dst, cntF, cntB);
    scan_kernel<<<2, 1024, 0, stream>>>(cntF, offF, cntB, offB);

    gemm_fill_kernel<<<NGEMM + FILLB, 256, 0, stream>>>(
        src, dst, offF, offB, curF, curB, listF, listB, Xb, Wb, Y, out);

    aggregate_kernel<<<N_NODES / (2 * NPW), 256, 0, stream>>>(
        Y, offF, listF, offB, listB, out);

    bn_stats_kernel<<<512, 256, 0, stream>>>(out, stats);
    bn_kernel<<<2048, 256, 0, stream>>>(stats, gamma, beta, out);
}

// Round 7
// 131.611 us; speedup vs baseline: 1.1526x; 1.1526x over previous
//
#include <hip/hip_runtime.h>
#include <hip/hip_bf16.h>

#define N_NODES 20000
#define N_EDGES 320000
#define BN_EPS  1e-5f

#define GEMM_MT  ((N_NODES + 127) / 128)    // 157
#define NGEMM    (GEMM_MT * 4)              // 628 GEMM blocks (first)
#define FILLB    625                        // 625*256*2 = 320000: 2 edges/thread

typedef __attribute__((ext_vector_type(4))) float f32x4;
typedef __attribute__((ext_vector_type(8))) __bf16 bf16x8;
typedef __attribute__((ext_vector_type(4))) unsigned short u16x4;

__device__ __forceinline__ unsigned short f2bf(float f) {   // RNE f32->bf16
    unsigned int u = __float_as_uint(f);
    u += 0x7fffu + ((u >> 16) & 1u);
    return (unsigned short)(u >> 16);
}
__device__ __forceinline__ float bflo(unsigned int u) { return __uint_as_float(u << 16); }
__device__ __forceinline__ float bfhi(unsigned int u) { return __uint_as_float(u & 0xffff0000u); }

__device__ __forceinline__ void gload_lds16(const void* g, void* l) {
    __builtin_amdgcn_global_load_lds(
        (const __attribute__((address_space(1))) void*)g,
        (__attribute__((address_space(3))) void*)l, 16, 0, 0);
}

// ---------------------------------------------------------------------------
// cvt + zero: convert x and the four W mats to bf16, and zero cnt/stats
// (replaces hipMemsetAsync, whose fill dispatch cost ~41 us in the graph).
// ---------------------------------------------------------------------------
__global__ __launch_bounds__(256) void cvt_zero_kernel(
    const float* __restrict__ x,
    const float* __restrict__ Wlf, const float* __restrict__ Wlb,
    const float* __restrict__ Wrf, const float* __restrict__ Wrb,
    unsigned short* __restrict__ Xb, unsigned short* __restrict__ Wb,
    uint4* __restrict__ zp, int zquads)
{
    const int XQ = N_NODES * 256 / 4;         // 1,280,000
    const int WQ = 128 * 256 / 4;             // 8,192 per matrix
    const int total = XQ + 4 * WQ + zquads;
    for (int i = blockIdx.x * blockDim.x + threadIdx.x; i < total; i += gridDim.x * blockDim.x) {
        if (i >= XQ + 4 * WQ) {
            zp[i - XQ - 4 * WQ] = make_uint4(0, 0, 0, 0);
            continue;
        }
        const float* sp;
        unsigned short* dp;
        if (i < XQ) {
            sp = x + (size_t)i * 4;
            dp = Xb + (size_t)i * 4;
        } else {
            int w = i - XQ;
            int mat = w / WQ;
            int o = (w - mat * WQ) * 4;
            if      (mat == 0) sp = Wlf + o;
            else if (mat == 1) sp = Wlb + o;
            else if (mat == 2) sp = Wrf + o;
            else               sp = Wrb + o;
            dp = Wb + (size_t)mat * 32768 + o;
        }
        float4 v = *(const float4*)sp;
        u16x4 r = {f2bf(v.x), f2bf(v.y), f2bf(v.z), f2bf(v.w)};
        *(u16x4*)dp = r;
    }
}

// ---------------------------------------------------------------------------
// count + rank capture: the atomicAdd return IS each edge's within-node rank.
// Persisting it (rank2 = pF | pB<<16, one coalesced store) makes the later
// fill phase atomic-free (round 5/6's 45us floor was the fill's dependent
// atomic->scatter chains). Ranks < ~64 << 65536, so 16 bits each is safe.
// ---------------------------------------------------------------------------
__global__ void count_rank_kernel(const int* __restrict__ src, const int* __restrict__ dst,
                                  int* __restrict__ cntF, int* __restrict__ cntB,
                                  unsigned int* __restrict__ rank2) {
    int e = blockIdx.x * blockDim.x + threadIdx.x;
    if (e < N_EDGES) {
        unsigned int p = (unsigned int)atomicAdd(&cntF[dst[e]], 1);
        unsigned int q = (unsigned int)atomicAdd(&cntB[src[e]], 1);
        rank2[e] = p | (q << 16);
    }
}

#define SCAN_PER 20
__global__ __launch_bounds__(1024) void scan_kernel(const int* __restrict__ cntF, int* __restrict__ offF,
                                                    const int* __restrict__ cntB, int* __restrict__ offB) {
    const int* in  = blockIdx.x ? cntB : cntF;
    int*       out = blockIdx.x ? offB : offF;
    int t = threadIdx.x;
    int base = t * SCAN_PER;
    int v[SCAN_PER];
    int sum = 0;
    #pragma unroll
    for (int k = 0; k < SCAN_PER; ++k) {
        int i = base + k;
        int c = (i < N_NODES) ? in[i] : 0;
        v[k] = sum; sum += c;
    }
    __shared__ int sh[1024];
    sh[t] = sum;
    __syncthreads();
    for (int o = 1; o < 1024; o <<= 1) {
        int x = (t >= o) ? sh[t - o] : 0;
        __syncthreads();
        sh[t] += x;
        __syncthreads();
    }
    int pre = t ? sh[t - 1] : 0;
    #pragma unroll
    for (int k = 0; k < SCAN_PER; ++k) {
        int i = base + k;
        if (i < N_NODES) out[i] = pre + v[k];
    }
    if (t == 1023) out[N_NODES] = sh[1023];
}

// ---------------------------------------------------------------------------
// Merged GEMM + fill. GEMM blocks first (blockIdx 0..NGEMM-1); fill blocks
// trail and are now ATOMIC-FREE (rank-capture): 2 independent scattered 4B
// stores per edge, no latency chain -> overlaps under the GEMM.
// GEMM: double-buffered BK=64 pipeline with counted vmcnt:
//   STAGE(t+1) -> s_waitcnt vmcnt(8) -> s_barrier -> MFMA(t) -> s_barrier
// XOR-swizzled staging (pre-swizzled source + swizzled ds_read; rule #21).
// ---------------------------------------------------------------------------
__global__ __launch_bounds__(256) void gemm_fill_kernel(
    const int* __restrict__ src, const int* __restrict__ dst,
    const int* __restrict__ offF, const int* __restrict__ offB,
    const unsigned int* __restrict__ rank2,
    int* __restrict__ listF, int* __restrict__ listB,
    const unsigned short* __restrict__ Xb, const unsigned short* __restrict__ Wb,
    unsigned short* __restrict__ Y, float* __restrict__ Z)
{
    __shared__ unsigned short As[2][128 * 64];   // 2 x 16 KB
    __shared__ unsigned short Bs[2][128 * 64];   // 2 x 16 KB

    if (blockIdx.x >= NGEMM) {
        // CSR fill: no atomics, pure scattered stores (rank precomputed)
        int t = (blockIdx.x - NGEMM) * 256 + threadIdx.x;   // 0..159999
        #pragma unroll
        for (int h = 0; h < 2; ++h) {
            int e = t + h * (N_EDGES / 2);
            int s = src[e], d = dst[e];
            unsigned int r2 = rank2[e];
            listF[offF[d] + (int)(r2 & 0xffffu)] = s;
            listB[offB[s] + (int)(r2 >> 16)] = d;
        }
        return;
    }

    int gb = blockIdx.x;
    int by = gb & 3;                 // 4 consecutive blocks share one Xb tile
    int mBase = (gb >> 2) * 128;
    int tid = threadIdx.x, lane = tid & 63, wave = tid >> 6;
    int wr = wave >> 1, wc = wave & 1;
    const unsigned short* W = Wb + (size_t)by * 128 * 256;

    f32x4 acc[4][4] = {};

    auto STAGE = [&](int b, int k0) {
        #pragma unroll
        for (int c = 0; c < 4; ++c) {
            int S = c * 256 + tid;                 // 16B slot index, 0..1023
            int row = S >> 3;
            int q = (S & 7) ^ (row & 7);           // pre-swizzled source slot
            int gm = mBase + row; gm = gm < N_NODES ? gm : N_NODES - 1;
            gload_lds16(Xb + (size_t)gm * 256 + k0 + q * 8, &As[b][S * 8]);
            gload_lds16(W + (size_t)row * 256 + k0 + q * 8, &Bs[b][S * 8]);
        }
    };
    auto COMPUTE = [&](int b) {
        #pragma unroll
        for (int ks = 0; ks < 2; ++ks) {
            bf16x8 af[4], bfr[4];
            int sl = ks * 4 + (lane >> 4);
            #pragma unroll
            for (int m = 0; m < 4; ++m) {
                int row = wr * 64 + m * 16 + (lane & 15);
                af[m] = *(const bf16x8*)&As[b][row * 64 + ((sl ^ (row & 7)) * 8)];
            }
            #pragma unroll
            for (int n = 0; n < 4; ++n) {
                int row = wc * 64 + n * 16 + (lane & 15);
                bfr[n] = *(const bf16x8*)&Bs[b][row * 64 + ((sl ^ (row & 7)) * 8)];
            }
            #pragma unroll
            for (int m = 0; m < 4; ++m)
                #pragma unroll
                for (int n = 0; n < 4; ++n)
                    acc[m][n] = __builtin_amdgcn_mfma_f32_16x16x32_bf16(af[m], bfr[n], acc[m][n], 0, 0, 0);
        }
    };

    STAGE(0, 0);                                   // prologue: tile 0 in flight
    #pragma unroll
    for (int t = 0; t < 4; ++t) {
        if (t < 3) {
            STAGE((t + 1) & 1, (t + 1) * 64);      // tile t+1 in flight (8 loads)
            asm volatile("s_waitcnt vmcnt(8)" ::: "memory");   // tile t done
        } else {
            asm volatile("s_waitcnt vmcnt(0)" ::: "memory");
        }
        __builtin_amdgcn_s_barrier();              // all waves: tile t ready
        __builtin_amdgcn_sched_barrier(0);
        COMPUTE(t & 1);
        __builtin_amdgcn_s_barrier();              // done reading buf before overwrite
    }

    bool toY = by < 2;
    int cBase = (by & 1) * 128 + wc * 64;
    #pragma unroll
    for (int m = 0; m < 4; ++m) {
        int gm0 = mBase + wr * 64 + m * 16 + (lane >> 4) * 4;
        #pragma unroll
        for (int n = 0; n < 4; ++n) {
            int gn = cBase + n * 16 + (lane & 15);
            f32x4 v = acc[m][n];
            #pragma unroll
            for (int j = 0; j < 4; ++j) {
                int gm = gm0 + j;
                if (gm < N_NODES) {
                    if (toY) Y[(size_t)gm * 256 + gn] = f2bf(v[j]);
                    else     Z[(size_t)gm * 256 + gn] = v[j];
                }
            }
        }
    }
}

// ---------------------------------------------------------------------------
// Aggregation: wave = one (node,dir) stream, 2 nodes/wave. 16 lanes cover one
// 128-col bf16 row (16B/lane), so one wave-load gathers 4 edges; 4 loads
// (16 edges) in flight. __shfl executes UNCONDITIONALLY (ds_bpermute reads 0
// from exec-inactive source lanes — round-4 bug); only the LOAD is predicated.
// Cross-group shfl_xor reduce, h = aggr/deg + Z.
// ---------------------------------------------------------------------------
#define NPW 2
__global__ __launch_bounds__(256) void aggregate_kernel(
    const unsigned short* __restrict__ Y,
    const int* __restrict__ offF, const int* __restrict__ listF,
    const int* __restrict__ offB, const int* __restrict__ listB,
    float* __restrict__ H)
{
    int tid = threadIdx.x, lane = tid & 63, wave = tid >> 6;
    int dir = wave >> 1, half = wave & 1;
    const int* off  = dir ? offB : offF;
    const int* list = dir ? listB : listF;
    int eg = lane >> 4;        // which edge of the group of 4
    int c16 = lane & 15;       // 16B column slot within the row
    int nodeBase = blockIdx.x * (2 * NPW) + half * NPW;

    for (int jn = 0; jn < NPW; ++jn) {
        int n = nodeBase + jn;                 // grid exact: always < N_NODES
        int beg = off[n], end = off[n + 1];
        int deg = end - beg;
        float acc[8] = {0.f, 0.f, 0.f, 0.f, 0.f, 0.f, 0.f, 0.f};

        for (int i = beg; i < end; i += 64) {
            int c = end - i; if (c > 64) c = 64;
            int u_l = list[i + (lane < c ? lane : 0)];
            for (int e0 = 0; e0 < c; e0 += 16) {
                uint4 v[4];
                #pragma unroll
                for (int k = 0; k < 4; ++k) {
                    int ei = e0 + k * 4 + eg;
                    // shfl with ALL lanes active (clamped index), then
                    // predicate only the memory access:
                    int u = __shfl(u_l, ei < c ? ei : 0);
                    v[k] = make_uint4(0u, 0u, 0u, 0u);
                    if (ei < c)
                        v[k] = *(const uint4*)(Y + (size_t)u * 256 + dir * 128 + c16 * 8);
                }
                #pragma unroll
                for (int k = 0; k < 4; ++k) {
                    acc[0] += bflo(v[k].x); acc[1] += bfhi(v[k].x);
                    acc[2] += bflo(v[k].y); acc[3] += bfhi(v[k].y);
                    acc[4] += bflo(v[k].z); acc[5] += bfhi(v[k].z);
                    acc[6] += bflo(v[k].w); acc[7] += bfhi(v[k].w);
                }
            }
        }
        #pragma unroll
        for (int j = 0; j < 8; ++j) {
            acc[j] += __shfl_xor(acc[j], 16);
            acc[j] += __shfl_xor(acc[j], 32);
        }
        // static-index select of this lane's two columns (rule #20)
        float h0 = (eg & 2) ? ((eg & 1) ? acc[6] : acc[4]) : ((eg & 1) ? acc[2] : acc[0]);
        float h1 = (eg & 2) ? ((eg & 1) ? acc[7] : acc[5]) : ((eg & 1) ? acc[3] : acc[1]);
        float inv = 1.f / fmaxf((float)deg, 1.f);
        float2* hp = (float2*)(H + (size_t)n * 256 + dir * 128 + c16 * 8 + eg * 2);
        float2 z = *hp;
        *hp = make_float2(fmaf(h0, inv, z.x), fmaf(h1, inv, z.y));
    }
}

// ---------------------------------------------------------------------------
// BN stats: column sums of H (coalesced, 512 atomics per block).
// ---------------------------------------------------------------------------
__global__ __launch_bounds__(256) void bn_stats_kernel(const float* __restrict__ H,
                                                       float* __restrict__ stats) {
    int col = threadIdx.x;
    float s1 = 0.f, s2 = 0.f;
    for (int n = blockIdx.x; n < N_NODES; n += gridDim.x) {
        float h = H[(size_t)n * 256 + col];
        s1 += h;
        s2 += h * h;
    }
    atomicAdd(&stats[col], s1);
    atomicAdd(&stats[256 + col], s2);
}

// ---------------------------------------------------------------------------
// BatchNorm finalize + ReLU, in place on d_out.
// ---------------------------------------------------------------------------
__global__ __launch_bounds__(256) void bn_kernel(
    const float* __restrict__ stats, const float* __restrict__ gamma,
    const float* __restrict__ beta, float* __restrict__ H)
{
    __shared__ float sc[256], sf[256];
    int tid = threadIdx.x;
    {
        float mean = stats[tid] * (1.f / N_NODES);
        float var  = stats[256 + tid] * (1.f / N_NODES) - mean * mean;
        float s = rsqrtf(fmaxf(var, 0.f) + BN_EPS) * gamma[tid];
        sc[tid] = s;
        sf[tid] = beta[tid] - mean * s;
    }
    __syncthreads();
    for (int n = blockIdx.x; n < N_NODES; n += gridDim.x) {
        size_t idx = (size_t)n * 256 + tid;
        float h = H[idx];
        H[idx] = fmaxf(h * sc[tid] + sf[tid], 0.f);
    }
}

// ---------------------------------------------------------------------------
extern "C" void kernel_launch(void* const* d_in, const int* in_sizes, int n_in,
                              void* d_out, int out_size, void* d_ws, size_t ws_size,
                              hipStream_t stream) {
    const float* x     = (const float*)d_in[0];
    const int*   edge  = (const int*)d_in[1];   // [2][N_EDGES]
    const float* Wlf   = (const float*)d_in[2];
    // d_in[3] = b_l_f : cancels under BatchNorm (per-column shift) - unused
    const float* Wrf   = (const float*)d_in[4];
    const float* Wlb   = (const float*)d_in[5];
    // d_in[6] = b_l_b : unused (cancels)
    const float* Wrb   = (const float*)d_in[7];
    const float* gamma = (const float*)d_in[8];
    const float* beta  = (const float*)d_in[9];
    float* out = (float*)d_out;

    const int* src = edge;
    const int* dst = edge + N_EDGES;

    char* ws = (char*)d_ws;
    size_t off = 0;
    auto alloc = [&](size_t bytes) { size_t r = off; off += (bytes + 255) & ~(size_t)255; return r; };
    unsigned short* Y  = (unsigned short*)(ws + alloc((size_t)N_NODES * 256 * 2)); // 10.24 MB
    unsigned short* Xb = (unsigned short*)(ws + alloc((size_t)N_NODES * 256 * 2)); // 10.24 MB
    unsigned short* Wb = (unsigned short*)(ws + alloc((size_t)4 * 128 * 256 * 2)); // 256 KB
    int* offF  = (int*)(ws + alloc((size_t)(N_NODES + 1) * 4));
    int* offB  = (int*)(ws + alloc((size_t)(N_NODES + 1) * 4));
    int* listF = (int*)(ws + alloc((size_t)N_EDGES * 4));
    int* listB = (int*)(ws + alloc((size_t)N_EDGES * 4));
    unsigned int* rank2 = (unsigned int*)(ws + alloc((size_t)N_EDGES * 4));        // 1.28 MB
    size_t zbase_off = off;
    int* cntF = (int*)(ws + alloc((size_t)N_NODES * 4));
    int* cntB = (int*)(ws + alloc((size_t)N_NODES * 4));
    float* stats = (float*)(ws + alloc(512 * 4));
    size_t zbytes = off - zbase_off;          // 256B-aligned => multiple of 16

    cvt_zero_kernel<<<2048, 256, 0, stream>>>(x, Wlf, Wlb, Wrf, Wrb, Xb, Wb,
                                              (uint4*)(ws + zbase_off), (int)(zbytes / 16));

    count_rank_kernel<<<(N_EDGES + 255) / 256, 256, 0, stream>>>(src, dst, cntF, cntB, rank2);
    scan_kernel<<<2, 1024, 0, stream>>>(cntF, offF, cntB, offB);

    gemm_fill_kernel<<<NGEMM + FILLB, 256, 0, stream>>>(
        src, dst, offF, offB, rank2, listF, listB, Xb, Wb, Y, out);

    aggregate_kernel<<<N_NODES / (2 * NPW), 256, 0, stream>>>(
        Y, offF, listF, offB, listB, out);

    bn_stats_kernel<<<512, 256, 0, stream>>>(out, stats);
    bn_kernel<<<2048, 256, 0, stream>>>(stats, gamma, beta, out);
}